// Round 9
// baseline (269.576 us; speedup 1.0000x reference)
//
#include <hip/hip_runtime.h>
#include <stdint.h>

// MultiHeadAttention: B=2, S=2048, D=1024, H=16, Dh=64. fp32 in/out, bf16 MFMA inside.
// R9: single-barrier double-buffered GEMM K-loop (the r8 2-barrier structure exposed
// full load latency every iteration at 1-3 blocks/CU); V-transpose fused into attn
// LDS staging (transpose kernel + HBM round trip deleted).

typedef unsigned short u16;
typedef short s16x8 __attribute__((ext_vector_type(8)));   // 8 bf16 (4 VGPR)
typedef short s16x4 __attribute__((ext_vector_type(4)));   // 4 bf16 (2 VGPR)
typedef float f32x4 __attribute__((ext_vector_type(4)));

#define S_LEN 2048
#define DMODEL 1024
#define LOG2E 1.44269504088896340736f

__device__ __forceinline__ u16 f2bf(float f) {
  union { float f; uint32_t u; } v; v.f = f;
  return (u16)((v.u + 0x8000u) >> 16);
}

__device__ __forceinline__ s16x8 ld8f(const float* s) {  // 8 fp32 -> 8 bf16
  f32x4 a = *(const f32x4*)s;
  f32x4 b = *(const f32x4*)(s + 4);
  s16x8 r;
  r[0] = (short)f2bf(a[0]); r[1] = (short)f2bf(a[1]);
  r[2] = (short)f2bf(a[2]); r[3] = (short)f2bf(a[3]);
  r[4] = (short)f2bf(b[0]); r[5] = (short)f2bf(b[1]);
  r[6] = (short)f2bf(b[2]); r[7] = (short)f2bf(b[3]);
  return r;
}

// async global->LDS, 16B/lane; HW scatters lane i to ldsbase + i*16
__device__ __forceinline__ void gl2lds16(const u16* g, u16* l) {
  __builtin_amdgcn_global_load_lds(
      (const __attribute__((address_space(1))) uint32_t*)g,
      (__attribute__((address_space(3))) uint32_t*)l, 16, 0, 0);
}

// ---------------------------------------------------------------------------
// fp32 -> bf16 conversion: 4 weights (1M elem) + 3 activations (4.19M elem).
// ---------------------------------------------------------------------------
struct Cvt7 { const float* s[7]; u16* d[7]; int n[7]; };

__global__ __launch_bounds__(256) void cvt7(Cvt7 p) {
  const int z = blockIdx.y;
  const int idx = blockIdx.x * 256 + threadIdx.x;
  if (idx * 8 < p.n[z])
    *(s16x8*)(p.d[z] + (size_t)idx * 8) = ld8f(p.s[z] + (size_t)idx * 8);
}

// ---------------------------------------------------------------------------
// GEMM: C[M,N] = A[M,K] @ W[N,K]^T + bias[N]; A,W bf16, bias fp32.
// OUT_F32=false -> C bf16 (QKV), OUT_F32=true -> C fp32 (O projection).
// 128x128 tile, BK=32, single-barrier double-buffered K-loop:
//   stage(buf0); loop { barrier; stage(buf^1, next); compute(buf); }
// The barrier's vmcnt(0) drains loads issued ONE ITERATION ago (hidden under
// ~1240 cyc of MFMA), not just-issued ones.
// LDS tile: 128x32 packed as [64 phys rows][8 chunks of 8 u16] (two M-halves:
// logical chunk lc = half*4 + kchunk, phys chunk = lc ^ (physrow & 7)).
// Fragment reads: 16 lanes -> 8 distinct chunks -> 2-way (free).
// 2 bufs x (As 8KB + Ws 8KB) = 32 KB -> 4+ blocks/CU.
// ---------------------------------------------------------------------------
struct GemmBatch {
  const u16* A[3]; const u16* W[3]; const float* Bv[3]; void* C[3];
};

template <bool OUT_F32>
__global__ __launch_bounds__(256) void gemm_bt(GemmBatch p, int M, int N, int K) {
  __shared__ u16 As[2][64 * 64];
  __shared__ u16 Ws[2][64 * 64];
  const int z = blockIdx.z;
  const u16* __restrict__ A      = p.A[z];
  const u16* __restrict__ W      = p.W[z];
  const float* __restrict__ bias = p.Bv[z];

  const int tid = threadIdx.x;
  const int wave = tid >> 6, lane = tid & 63;
  const int quad = lane >> 4, l16 = lane & 15;
  const int bm = blockIdx.y * 128, bn = blockIdx.x * 128;
  const int wr = (wave >> 1) * 64, wc = (wave & 1) * 64;
  const int ha = wr >> 6, hb = wc >> 6;   // M-half of this wave's A/B rows

  // staging geometry: instr i covers phys rows wave*16+i*8 .. +8, all 8 chunks
  const int pr8 = lane >> 3;          // phys row within instr
  const int pc  = lane & 7;           // phys chunk this lane lands in
  const int lc  = pc ^ pr8;           // logical chunk to fetch (swizzle)
  const int hh  = lc >> 2;            // M-half (0: rows 0-63, 1: 64-127)
  const int kc  = lc & 3;             // k-chunk (8 u16)

  size_t goff[2];
#pragma unroll
  for (int i = 0; i < 2; i++) {
    const int prow = wave * 16 + i * 8 + pr8;
    goff[i] = (size_t)(hh * 64 + prow) * K + kc * 8;
  }

  f32x4 acc[4][4];
#pragma unroll
  for (int i = 0; i < 4; i++)
#pragma unroll
    for (int j = 0; j < 4; j++) acc[i][j] = {0.f, 0.f, 0.f, 0.f};

  const u16* Ab = A + (size_t)bm * K;
  const u16* Wb = W + (size_t)bn * K;

  // prologue: stage tile 0 into buffer 0
#pragma unroll
  for (int i = 0; i < 2; i++) {
    gl2lds16(Ab + goff[i], &As[0][(wave * 16 + i * 8) * 64]);
    gl2lds16(Wb + goff[i], &Ws[0][(wave * 16 + i * 8) * 64]);
  }

  const int NIT = K / 32;
  for (int it = 0; it < NIT; it++) {
    const int cur = it & 1;
    __syncthreads();  // buf[cur] loads (1 iter old) landed; prev reads done
    if (it + 1 < NIT) {
      const int kt2 = (it + 1) * 32;
#pragma unroll
      for (int i = 0; i < 2; i++) {
        gl2lds16(Ab + goff[i] + kt2, &As[cur ^ 1][(wave * 16 + i * 8) * 64]);
        gl2lds16(Wb + goff[i] + kt2, &Ws[cur ^ 1][(wave * 16 + i * 8) * 64]);
      }
    }

    s16x8 a[4], b[4];
#pragma unroll
    for (int t = 0; t < 4; t++)
      a[t] = *(const s16x8*)&As[cur][(t * 16 + l16) * 64 +
                                     (((ha * 4 + quad) ^ (l16 & 7)) << 3)];
#pragma unroll
    for (int t = 0; t < 4; t++)
      b[t] = *(const s16x8*)&Ws[cur][(t * 16 + l16) * 64 +
                                     (((hb * 4 + quad) ^ (l16 & 7)) << 3)];
#pragma unroll
    for (int i = 0; i < 4; i++)
#pragma unroll
      for (int j = 0; j < 4; j++)
        acc[i][j] = __builtin_amdgcn_mfma_f32_16x16x32_bf16(a[i], b[j], acc[i][j], 0, 0, 0);
  }

  // epilogue: C/D layout row = quad*4 + reg, col = lane&15
#pragma unroll
  for (int j = 0; j < 4; j++) {
    const int col = bn + wc + j * 16 + l16;
    const float bv = bias[col];
#pragma unroll
    for (int i = 0; i < 4; i++) {
      const int row0 = bm + wr + i * 16 + quad * 4;
#pragma unroll
      for (int r = 0; r < 4; r++) {
        const float val = acc[i][j][r] + bv;
        if (OUT_F32)
          ((float*)p.C[z])[(size_t)(row0 + r) * N + col] = val;
        else
          ((u16*)p.C[z])[(size_t)(row0 + r) * N + col] = f2bf(val);
      }
    }
  }
}

// ---------------------------------------------------------------------------
// Flash attention, transposed softmax, per-16-kv subtile S^T->exp->pack->PV.
// V is read from natural-layout Vp and transposed during LDS staging via
// swizzled ds_write_b16 scatter (replaces the separate transpose kernel).
// ---------------------------------------------------------------------------
__global__ __launch_bounds__(256, 2) void attn_kernel(const u16* __restrict__ Qp,
                                                      const u16* __restrict__ Kp,
                                                      const u16* __restrict__ Vp,
                                                      u16* __restrict__ AO) {
  __shared__ u16 Qs[128 * 64];   // [q][d]   16 KB, 8-chunk XOR swizzle
  __shared__ u16 Ks[128 * 64];   // [kv][d]  16 KB, 8-chunk XOR swizzle
  __shared__ u16 Vs[64 * 128];   // [d][kv]  16 KB, 16-chunk XOR swizzle

  const int tid = threadIdx.x;
  const int wave = tid >> 6, lane = tid & 63;
  const int quad = lane >> 4, l16 = lane & 15;
  const int bh = blockIdx.y, b = bh >> 4, h = bh & 15;
  const int s0 = blockIdx.x * 128;
  const float c = 0.03125f * LOG2E;  // d_model^-0.5 * log2(e)

  const int qr = lane >> 3, qc = lane & 7;   // Q/K/V load: row-in-8, d-chunk

#pragma unroll
  for (int i = 0; i < 4; i++) {
    const int rr = i * 32 + wave * 8 + qr;
    s16x8 qv = *(const s16x8*)(Qp + (size_t)(b * S_LEN + s0 + rr) * DMODEL + h * 64 + qc * 8);
    *(s16x8*)&Qs[rr * 64 + ((qc ^ qr) << 3)] = qv;
  }
  __syncthreads();

  s16x8 aq[2][2];
#pragma unroll
  for (int ks = 0; ks < 2; ks++)
#pragma unroll
    for (int rt = 0; rt < 2; rt++) {
      const int row = wave * 32 + rt * 16 + l16;
      const int ch = ks * 4 + quad;
      aq[ks][rt] = *(const s16x8*)&Qs[row * 64 + ((ch ^ (l16 & 7)) << 3)];
    }

  // prefetch K/V tile 0 (V from natural layout: same pattern as K)
  s16x8 kv[4], vv[4];
#pragma unroll
  for (int i = 0; i < 4; i++) {
    const int rr = i * 32 + wave * 8 + qr;
    kv[i] = *(const s16x8*)(Kp + (size_t)(b * S_LEN + rr) * DMODEL + h * 64 + qc * 8);
    vv[i] = *(const s16x8*)(Vp + (size_t)(b * S_LEN + rr) * DMODEL + h * 64 + qc * 8);
  }

  f32x4 o[2][4];
  float l_r[2] = {0.f, 0.f};
#pragma unroll
  for (int rt = 0; rt < 2; rt++)
#pragma unroll
    for (int dt = 0; dt < 4; dt++) o[rt][dt] = {0.f, 0.f, 0.f, 0.f};

  const f32x4 zf = {0.f, 0.f, 0.f, 0.f};

  for (int kt = 0; kt < S_LEN; kt += 128) {
    __syncthreads();
#pragma unroll
    for (int i = 0; i < 4; i++) {
      const int rr = i * 32 + wave * 8 + qr;
      *(s16x8*)&Ks[rr * 64 + ((qc ^ qr) << 3)] = kv[i];
    }
    // V transpose-on-store: lane holds 8 d's (d = qc*8+j) of kv row rr.
    // Vs[d][kv] with phys 16B chunk = (kv>>3) ^ (d&15); kv>>3 = i*4+wave.
#pragma unroll
    for (int i = 0; i < 4; i++) {
      const int cch = i * 4 + wave;   // kv chunk (uniform per i)
#pragma unroll
      for (int j = 0; j < 8; j++) {
        const int d = qc * 8 + j;
        Vs[d * 128 + ((cch ^ (d & 15)) << 3) + qr] = (u16)vv[i][j];
      }
    }
    __syncthreads();

    if (kt + 128 < S_LEN) {
      const int k2 = kt + 128;
#pragma unroll
      for (int i = 0; i < 4; i++) {
        const int rr = i * 32 + wave * 8 + qr;
        kv[i] = *(const s16x8*)(Kp + (size_t)(b * S_LEN + k2 + rr) * DMODEL + h * 64 + qc * 8);
        vv[i] = *(const s16x8*)(Vp + (size_t)(b * S_LEN + k2 + rr) * DMODEL + h * 64 + qc * 8);
      }
    }

#pragma unroll
    for (int kvt = 0; kvt < 8; kvt++) {
      const int krow = kvt * 16 + l16;
      s16x8 ak0 = *(const s16x8*)&Ks[krow * 64 + (((0 + quad) ^ (l16 & 7)) << 3)];
      s16x8 ak1 = *(const s16x8*)&Ks[krow * 64 + (((4 + quad) ^ (l16 & 7)) << 3)];
      f32x4 sA, sB;
      sA = __builtin_amdgcn_mfma_f32_16x16x32_bf16(ak0, aq[0][0], zf, 0, 0, 0);
      sA = __builtin_amdgcn_mfma_f32_16x16x32_bf16(ak1, aq[1][0], sA, 0, 0, 0);
      sB = __builtin_amdgcn_mfma_f32_16x16x32_bf16(ak0, aq[0][1], zf, 0, 0, 0);
      sB = __builtin_amdgcn_mfma_f32_16x16x32_bf16(ak1, aq[1][1], sB, 0, 0, 0);

      s16x4 pf0, pf1;
      float rs0 = 0.f, rs1 = 0.f;
#pragma unroll
      for (int r = 0; r < 4; r++) {
        const float p0 = exp2f(sA[r] * c);
        const float p1 = exp2f(sB[r] * c);
        rs0 += p0; rs1 += p1;
        pf0[r] = (short)f2bf(p0);
        pf1[r] = (short)f2bf(p1);
      }
      l_r[0] += rs0; l_r[1] += rs1;

      const int ch = kvt * 2 + (quad >> 1);
#pragma unroll
      for (int dt = 0; dt < 4; dt++) {
        const int row = dt * 16 + l16;
        s16x4 bv = *(const s16x4*)&Vs[row * 128 + ((ch ^ l16) << 3) + (quad & 1) * 4];
        o[0][dt] = __builtin_amdgcn_mfma_f32_16x16x16bf16_1k(pf0, bv, o[0][dt], 0, 0, 0);
        o[1][dt] = __builtin_amdgcn_mfma_f32_16x16x16bf16_1k(pf1, bv, o[1][dt], 0, 0, 0);
      }
    }
  }

#pragma unroll
  for (int rt = 0; rt < 2; rt++) {
    l_r[rt] += __shfl_xor(l_r[rt], 16);
    l_r[rt] += __shfl_xor(l_r[rt], 32);
  }
#pragma unroll
  for (int rt = 0; rt < 2; rt++) {
#pragma unroll
    for (int r = 0; r < 4; r++) {
      const float linv = 1.f / __shfl(l_r[rt], quad * 4 + r);
      const int row = s0 + wave * 32 + rt * 16 + quad * 4 + r;
#pragma unroll
      for (int dt = 0; dt < 4; dt++)
        AO[(size_t)(b * S_LEN + row) * DMODEL + h * 64 + dt * 16 + l16] =
            f2bf(o[rt][dt][r] * linv);
    }
  }
}

// ---------------------------------------------------------------------------
extern "C" void kernel_launch(void* const* d_in, const int* in_sizes, int n_in,
                              void* d_out, int out_size, void* d_ws, size_t ws_size,
                              hipStream_t stream) {
  const float* query = (const float*)d_in[0];
  const float* key_  = (const float*)d_in[1];
  const float* value = (const float*)d_in[2];
  const float* W_q = (const float*)d_in[3];
  const float* b_q = (const float*)d_in[4];
  const float* W_k = (const float*)d_in[5];
  const float* b_k = (const float*)d_in[6];
  const float* W_v = (const float*)d_in[7];
  const float* b_v = (const float*)d_in[8];
  const float* W_o = (const float*)d_in[9];
  const float* b_o = (const float*)d_in[10];
  float* out = (float*)d_out;

  const int M = 2 * S_LEN;  // 4096
  const int N = DMODEL, K = DMODEL;
  const size_t WSZ = (size_t)DMODEL * DMODEL;   // 1,048,576
  const size_t SZ  = (size_t)M * DMODEL;        // 4,194,304

  u16* Wqb = (u16*)d_ws;
  u16* Wkb = Wqb + WSZ;
  u16* Wvb = Wkb + WSZ;
  u16* Wob = Wvb + WSZ;
  u16* Qa  = Wob + WSZ;          // bf16 inputs
  u16* Ka  = Qa + SZ;
  u16* Va  = Ka + SZ;
  u16* Qp  = Va + SZ;            // projections
  u16* Kp  = Qp + SZ;
  u16* Vp  = Kp + SZ;
  u16* AO  = Qp;                 // aliases Qp (per-block disjoint read->write)

  Cvt7 cw;
  cw.s[0] = W_q;   cw.d[0] = Wqb; cw.n[0] = (int)WSZ;
  cw.s[1] = W_k;   cw.d[1] = Wkb; cw.n[1] = (int)WSZ;
  cw.s[2] = W_v;   cw.d[2] = Wvb; cw.n[2] = (int)WSZ;
  cw.s[3] = W_o;   cw.d[3] = Wob; cw.n[3] = (int)WSZ;
  cw.s[4] = query; cw.d[4] = Qa;  cw.n[4] = (int)SZ;
  cw.s[5] = key_;  cw.d[5] = Ka;  cw.n[5] = (int)SZ;
  cw.s[6] = value; cw.d[6] = Va;  cw.n[6] = (int)SZ;
  cvt7<<<dim3((int)(SZ / 2048), 7), 256, 0, stream>>>(cw);

  GemmBatch p1;
  p1.A[0] = Qa; p1.W[0] = Wqb; p1.Bv[0] = b_q; p1.C[0] = Qp;
  p1.A[1] = Ka; p1.W[1] = Wkb; p1.Bv[1] = b_k; p1.C[1] = Kp;
  p1.A[2] = Va; p1.W[2] = Wvb; p1.Bv[2] = b_v; p1.C[2] = Vp;
  gemm_bt<false><<<dim3(N / 128, M / 128, 3), 256, 0, stream>>>(p1, M, N, K);

  attn_kernel<<<dim3(S_LEN / 128, 32), 256, 0, stream>>>(Qp, Kp, Vp, AO);

  GemmBatch p2;
  p2.A[0] = AO; p2.W[0] = Wob; p2.Bv[0] = b_o; p2.C[0] = out;
  p2.A[1] = AO; p2.W[1] = Wob; p2.Bv[1] = b_o; p2.C[1] = out;
  p2.A[2] = AO; p2.W[2] = Wob; p2.Bv[2] = b_o; p2.C[2] = out;
  gemm_bt<true><<<dim3(N / 128, M / 128, 1), 256, 0, stream>>>(p2, M, N, K);
}